// Round 4
// baseline (218.065 us; speedup 1.0000x reference)
//
#include <hip/hip_runtime.h>
#include <hip/hip_cooperative_groups.h>

namespace cg = cooperative_groups;

#define BB 4
#define NN 4096
#define EE 1024
#define FIN 128
#define FE 64
#define CAP 33        // max edges per node (Poisson mean 2.05)
#define LSTRIDE 34
#define CAPE 40       // max nodes per edge (Poisson mean 8.2)

#define VB_LISTS 4096
#define VB_HEPE  1024
#define VB_DINV  64
#define VB_GEMM  512
#define NVB_A (VB_LISTS + VB_HEPE + VB_DINV + VB_GEMM)   // 5696
#define NVB_B 4096

typedef unsigned short u16;
typedef unsigned long long u64;

// phases: 0 = zero ecnt, 1 = {lists+escatter | hepe | dinv | gemm}, 2 = main
// coop=1: run all phases with grid.sync() between (single cooperative launch)
__global__ __launch_bounds__(256) void k_fused(
    const float* __restrict__ T,     const float* __restrict__ edge,
    const float* __restrict__ ew,    const float* __restrict__ D,
    const float* __restrict__ node,  const float* __restrict__ W,
    const float* __restrict__ A,
    float* __restrict__ hepe,        float* __restrict__ dinv,
    u16*   __restrict__ lists,       int* __restrict__ ecnt,
    u16*   __restrict__ elists,
    float* __restrict__ nodeW,       float* __restrict__ out,
    int coop, int phase, int withGemm)
{
    __shared__ float tile[32][FIN];
    int t = threadIdx.x, lane = t & 63, wid = t >> 6;
    int nb = gridDim.x;

    // ---------- phase 0: zero ecnt ----------
    if (coop || phase == 0) {
        for (int i = blockIdx.x * 256 + t; i < BB * EE; i += nb * 256) ecnt[i] = 0;
    }
    if (coop) cg::this_grid().sync();
    else if (phase == 0) return;

    // ---------- phase A ----------
    if (coop || phase == 1) {
        for (int vb = blockIdx.x; vb < NVB_A; vb += nb) {
            if (vb < VB_LISTS) {
                // per-node edge list from T + writer-lane scatter into per-edge lists
                int row = vb * 4 + wid;                 // b*N + n
                int b = row >> 12, n = row & (NN - 1);
                const float4* rowT = (const float4*)(T + (size_t)row * EE);
                u16* L = lists + (size_t)row * LSTRIDE;
                int base = 0;
#pragma unroll
                for (int i = 0; i < 4; i++) {
                    float4 tv = rowT[i * 64 + lane];
                    float vs[4] = {tv.x, tv.y, tv.z, tv.w};
                    int c = (tv.x != 0.f) + (tv.y != 0.f) + (tv.z != 0.f) + (tv.w != 0.f);
                    int x = c;
#pragma unroll
                    for (int d = 1; d < 64; d <<= 1) {
                        int o = __shfl_up(x, d, 64);
                        if (lane >= d) x += o;
                    }
                    int tot = __shfl(x, 63, 64);
                    int pos = base + x - c;
#pragma unroll
                    for (int s = 0; s < 4; s++) {
                        if (vs[s] != 0.f) {
                            if (pos < CAP) {
                                int e = (i * 64 + lane) * 4 + s;
                                L[1 + pos] = (u16)e;
                                int eb = (b << 10) + e;
                                int p2 = atomicAdd(&ecnt[eb], 1);
                                if (p2 < CAPE) elists[(size_t)eb * CAPE + p2] = (u16)n;
                            }
                            pos++;
                        }
                    }
                    base += tot;
                }
                if (lane == 0) L[0] = (u16)(base < CAP ? base : CAP);
            } else if (vb < VB_LISTS + VB_HEPE) {
                // HePe[b,e] = dot(edge[b,e,:], edge_weight)
                int row = (vb - VB_LISTS) * 4 + wid;    // b*E + e
                float v = edge[(size_t)row * FE + lane] * ew[lane];
#pragma unroll
                for (int d = 32; d >= 1; d >>= 1) v += __shfl_xor(v, d, 64);
                if (lane == 0) hepe[row] = v;
            } else if (vb < VB_LISTS + VB_HEPE + VB_DINV) {
                // dinv[b,n] = 1/sqrt(D[b,n,n])
                int idx = (vb - VB_LISTS - VB_HEPE) * 256 + t;  // b*N + n
                int b = idx >> 12, n = idx & (NN - 1);
                float v = D[((size_t)b * NN + n) * NN + n];
                dinv[idx] = (v != 0.f) ? (1.f / sqrtf(v)) : 0.f;
            } else if (withGemm) {
                // nodeW = node @ W (32 rows per vblock)
                size_t row0 = (size_t)(vb - VB_LISTS - VB_HEPE - VB_DINV) * 32;
                const float* sbase = node + row0 * FIN;
                float* dbase = nodeW + row0 * FIN;
#pragma unroll
                for (int k = 0; k < 16; k++) {
                    int idx = k * 256 + t;
                    tile[idx >> 7][idx & 127] = sbase[idx];
                }
                __syncthreads();
                int f = t & 127, h = t >> 7;
                float acc[16];
#pragma unroll
                for (int j = 0; j < 16; j++) acc[j] = 0.f;
                for (int k = 0; k < 128; k += 2) {
                    float w0 = W[k * 128 + f];
                    float w1 = W[(k + 1) * 128 + f];
#pragma unroll
                    for (int j = 0; j < 16; j++) {
                        float2 tv = *(const float2*)&tile[h * 16 + j][k];
                        acc[j] += tv.x * w0 + tv.y * w1;
                    }
                }
#pragma unroll
                for (int j = 0; j < 16; j++) dbase[(size_t)(h * 16 + j) * 128 + f] = acc[j];
                __syncthreads();   // tile reused if this block gets another gemm vb
            }
        }
    }
    if (coop) cg::this_grid().sync();
    else if (phase == 1) return;

    // ---------- phase B: out[n,:] = sum_{e in edges(n), m in nodes(e)} h[e]*(A+I)[n,m]*dinv[m]*rows[m,:]
    const float2* rows2 = (const float2*)nodeW;
    float2* out2 = (float2*)out;
    for (int vb = blockIdx.x; vb < NVB_B; vb += nb) {
        int row = vb * 4 + wid;                  // b*N + n
        int b = row >> 12, n = row & (NN - 1);
        const u16* L = lists + (size_t)row * LSTRIDE;
        int cn = L[0];
        int eReg = 0; float hReg = 0.f;
        if (lane < cn) {
            eReg = L[1 + lane];
            hReg = hepe[(b << 10) + eReg];
        }
        float2 acc = make_float2(0.f, 0.f);
        for (int j = 0; j < cn; j++) {
            int   e = __shfl(eReg, j, 64);
            float h = __shfl(hReg, j, 64);
            int eb = (b << 10) + e;
            int cm = ecnt[eb];
            if (cm > CAPE) cm = CAPE;
            float c = 0.f; int m = 0;
            if (lane < cm) {
                m = elists[(size_t)eb * CAPE + lane];
                float a = A[((size_t)b << 24) + ((size_t)n << 12) + m];
                if (m == n) a += 1.f;            // A = node_adj + I
                if (a != 0.f) c = h * a * dinv[(b << 12) + m];
            }
            u64 mask = __ballot(c != 0.f);
            while (mask) {
                int src = __ffsll(mask) - 1;
                mask &= mask - 1;
                float cb = __shfl(c, src, 64);
                int   mb = __shfl(m, src, 64);
                float2 nv = rows2[((size_t)((b << 12) + mb)) * 64 + lane];
                acc.x += cb * nv.x;
                acc.y += cb * nv.y;
            }
        }
        out2[(size_t)row * 64 + lane] = acc;
    }
}

// fallback epilogue for the (unlikely) no-workspace path: in-place out = out @ W
__global__ __launch_bounds__(256) void k_gemm(const float* __restrict__ src,
                                              const float* __restrict__ W,
                                              float* __restrict__ dst) {
    __shared__ float tile[32][FIN];
    int t = threadIdx.x;
    size_t row0 = (size_t)blockIdx.x * 32;
    const float* sbase = src + row0 * FIN;
    float* dbase = dst + row0 * FIN;
#pragma unroll
    for (int k = 0; k < 16; k++) {
        int idx = k * 256 + t;
        tile[idx >> 7][idx & 127] = sbase[idx];
    }
    __syncthreads();
    int f = t & 127, h = t >> 7;
    float acc[16];
#pragma unroll
    for (int j = 0; j < 16; j++) acc[j] = 0.f;
    for (int k = 0; k < 128; k += 2) {
        float w0 = W[k * 128 + f];
        float w1 = W[(k + 1) * 128 + f];
#pragma unroll
        for (int j = 0; j < 16; j++) {
            float2 tv = *(const float2*)&tile[h * 16 + j][k];
            acc[j] += tv.x * w0 + tv.y * w1;
        }
    }
#pragma unroll
    for (int j = 0; j < 16; j++) dbase[(size_t)(h * 16 + j) * 128 + f] = acc[j];
}

extern "C" void kernel_launch(void* const* d_in, const int* in_sizes, int n_in,
                              void* d_out, int out_size, void* d_ws, size_t ws_size,
                              hipStream_t stream) {
    const float* node     = (const float*)d_in[0];
    const float* edge     = (const float*)d_in[1];
    const float* node_adj = (const float*)d_in[2];
    const float* D        = (const float*)d_in[3];
    const float* T        = (const float*)d_in[4];
    const float* ew       = (const float*)d_in[5];
    const float* W        = (const float*)d_in[6];
    float* out = (float*)d_out;

    // workspace layout
    char* ws = (char*)d_ws;
    float* hepe  = (float*)ws;                          ws += BB * EE * 4;
    float* dinv  = (float*)ws;                          ws += BB * NN * 4;
    int*   ecnt  = (int*)ws;                            ws += BB * EE * 4;
    u16*   lists = (u16*)ws;                            ws += BB * NN * LSTRIDE * 2;
    u16*   elists= (u16*)ws;                            ws += BB * EE * CAPE * 2;
    size_t small_need = (size_t)(ws - (char*)d_ws);
    float* nodeW = (float*)ws;                          // 8.39 MB (optional)
    bool fuse = ws_size >= small_need + (size_t)BB * NN * FIN * 4;

    // co-residency-clamped grid for cooperative launch
    int dev = 0; hipGetDevice(&dev);
    int ncu = 0; hipDeviceGetAttribute(&ncu, hipDeviceAttributeMultiprocessorCount, dev);
    int occ = 0; hipOccupancyMaxActiveBlocksPerMultiprocessor(&occ, k_fused, 256, 0);
    if (ncu <= 0) ncu = 256;
    if (occ <= 0) occ = 4;
    long grid = (long)occ * ncu;
    if (grid > 2048) grid = 2048;

    bool coopDone = false;
    if (fuse) {
        const float* Tp = T; const float* edgep = edge; const float* ewp = ew;
        const float* Dp = D; const float* nodep = node; const float* Wp = W;
        const float* Ap = node_adj;
        float* hepep = hepe; float* dinvp = dinv; u16* listsp = lists;
        int* ecntp = ecnt; u16* elistsp = elists; float* nodeWp = nodeW;
        float* outp = out;
        int coopv = 1, phasev = -1, wg = 1;
        void* args[] = {&Tp, &edgep, &ewp, &Dp, &nodep, &Wp, &Ap,
                        &hepep, &dinvp, &listsp, &ecntp, &elistsp,
                        &nodeWp, &outp, &coopv, &phasev, &wg};
        hipError_t e = hipLaunchCooperativeKernel(k_fused, dim3((unsigned)grid),
                                                  dim3(256), args, 0u, stream);
        coopDone = (e == hipSuccess);
    }

    if (!coopDone) {
        // non-cooperative fallback: 3 dispatches (+ in-place gemm if no workspace)
        float* rows = fuse ? nodeW : (float*)node;
        k_fused<<<16,     256, 0, stream>>>(T, edge, ew, D, node, W, node_adj,
                                            hepe, dinv, lists, ecnt, elists,
                                            nodeW, out, 0, 0, fuse ? 1 : 0);
        k_fused<<<NVB_A,  256, 0, stream>>>(T, edge, ew, D, node, W, node_adj,
                                            hepe, dinv, lists, ecnt, elists,
                                            nodeW, out, 0, 1, fuse ? 1 : 0);
        k_fused<<<NVB_B,  256, 0, stream>>>(T, edge, ew, D, node, W, node_adj,
                                            hepe, dinv, lists, ecnt, elists,
                                            rows, out, 0, 2, fuse ? 1 : 0);
        if (!fuse) k_gemm<<<BB * NN / 32, 256, 0, stream>>>(out, W, out);
    }
}

// Round 5
// 55.131 us; speedup vs baseline: 3.9554x; 3.9554x over previous
//
#include <hip/hip_runtime.h>

#define BB 4
#define NN 4096
#define EE 1024
#define FIN 128
#define FE 64
#define CAP 33        // max edges per node (Poisson mean 2.05)
#define LSTRIDE 34
#define CAPE 40       // max nodes per edge (Poisson mean 8.2)

typedef unsigned short u16;
typedef unsigned int u32;
typedef unsigned long long u64;

// ---------------- K_misc: {hepe + zero ecnt} | {dinv} ----------------
__global__ __launch_bounds__(256) void k_misc(const float* __restrict__ edge,
                                              const float* __restrict__ ew,
                                              const float* __restrict__ D,
                                              float* __restrict__ hepe,
                                              int* __restrict__ ecnt,
                                              float* __restrict__ dinv) {
    int t = threadIdx.x, lane = t & 63, wid = t >> 6;
    int bid = blockIdx.x;
    if (bid < BB * EE / 4) {
        int row = bid * 4 + wid;                 // b*E + e
        float v = edge[(size_t)row * FE + lane] * ew[lane];
#pragma unroll
        for (int d = 32; d >= 1; d >>= 1) v += __shfl_xor(v, d, 64);
        if (lane == 0) { hepe[row] = v; ecnt[row] = 0; }
    } else {
        int idx = (bid - BB * EE / 4) * 256 + t; // b*N + n
        int b = idx >> 12, n = idx & (NN - 1);
        float v = D[((size_t)b * NN + n) * NN + n];
        dinv[idx] = (v != 0.f) ? (1.f / sqrtf(v)) : 0.f;
    }
}

// ---------------- K_lists: per-node edge list + fused per-edge scatter ----------------
__global__ __launch_bounds__(256) void k_lists(const float* __restrict__ T,
                                               u16* __restrict__ lists,
                                               int* __restrict__ ecnt,
                                               u16* __restrict__ elists) {
    int t = threadIdx.x, lane = t & 63, wid = t >> 6;
    int row = blockIdx.x * 4 + wid;              // b*N + n
    int b = row >> 12, n = row & (NN - 1);
    const float4* rowT = (const float4*)(T + (size_t)row * EE);
    // 4 independent loads up front (MLP), one scan per row
    float4 t0 = rowT[lane], t1 = rowT[64 + lane], t2 = rowT[128 + lane], t3 = rowT[192 + lane];
    float vs[16] = {t0.x, t0.y, t0.z, t0.w, t1.x, t1.y, t1.z, t1.w,
                    t2.x, t2.y, t2.z, t2.w, t3.x, t3.y, t3.z, t3.w};
    int c = 0;
#pragma unroll
    for (int k = 0; k < 16; k++) c += (vs[k] != 0.f);
    int x = c;
#pragma unroll
    for (int d = 1; d < 64; d <<= 1) {
        int o = __shfl_up(x, d, 64);
        if (lane >= d) x += o;
    }
    int tot = __shfl(x, 63, 64);
    int pos = x - c;                             // exclusive prefix
    u16* L = lists + (size_t)row * LSTRIDE;
    if (c > 0) {
#pragma unroll
        for (int k = 0; k < 16; k++) {
            if (vs[k] != 0.f) {
                if (pos < CAP) {
                    int e = ((k >> 2) * 64 + lane) * 4 + (k & 3);
                    L[1 + pos] = (u16)e;
                    int eb = (b << 10) + e;
                    int p2 = atomicAdd(&ecnt[eb], 1);
                    if (p2 < CAPE) elists[(size_t)eb * CAPE + p2] = (u16)n;
                }
                pos++;
            }
        }
    }
    if (lane == 0) L[0] = (u16)(tot < CAP ? tot : CAP);
}

// ---------------- K_gemm: dst = src @ W (32 rows/block; in-place safe) ----------------
__global__ __launch_bounds__(256) void k_gemm(const float* __restrict__ src,
                                              const float* __restrict__ W,
                                              float* __restrict__ dst) {
    __shared__ float tile[32][FIN];
    int t = threadIdx.x;
    size_t row0 = (size_t)blockIdx.x * 32;
    const float* sbase = src + row0 * FIN;
    float* dbase = dst + row0 * FIN;
#pragma unroll
    for (int k = 0; k < 16; k++) {
        int idx = k * 256 + t;
        tile[idx >> 7][idx & 127] = sbase[idx];
    }
    __syncthreads();
    int f = t & 127, h = t >> 7;
    float acc[16];
#pragma unroll
    for (int j = 0; j < 16; j++) acc[j] = 0.f;
    for (int k = 0; k < 128; k += 2) {
        float w0 = W[k * 128 + f];
        float w1 = W[(k + 1) * 128 + f];
#pragma unroll
        for (int j = 0; j < 16; j++) {
            float2 tv = *(const float2*)&tile[h * 16 + j][k];
            acc[j] += tv.x * w0 + tv.y * w1;
        }
    }
#pragma unroll
    for (int j = 0; j < 16; j++) dbase[(size_t)(h * 16 + j) * 128 + f] = acc[j];
}

// ---------------- K_main: flat-pair evaluation ----------------
// out[n,:] = sd*(A[n,n]+1)*dinv[n]*rows[n,:]
//          + sum over pairs (e in edges(n), m in nodes(e), m!=n) h[e]*A[n,m]*dinv[m]*rows[m,:]
__global__ __launch_bounds__(256) void k_main(const float* __restrict__ A,
                                              const float* __restrict__ rows,
                                              const float* __restrict__ hepe,
                                              const float* __restrict__ dinv,
                                              const u16* __restrict__ lists,
                                              const int* __restrict__ ecnt,
                                              const u16* __restrict__ elists,
                                              float* __restrict__ out) {
    __shared__ u16   sOFF[4][34];
    __shared__ float sH[4][34];
    __shared__ u32   sEB[4][34];
    int t = threadIdx.x, lane = t & 63, wid = t >> 6;
    int row = blockIdx.x * 4 + wid;              // b*N + n
    int b = row >> 12, n = row & (NN - 1);
    const u16* L = lists + (size_t)row * LSTRIDE;

    // --- one parallel metadata hop: all edges' {e, cnt, h} at once ---
    int cn = L[0];
    int eRaw = 0;
    if (lane <= 32) eRaw = L[1 + lane];          // lanes beyond cn read junk, masked below
    int eb = (b << 10) + (eRaw & (EE - 1));      // clamp keeps gathers in-bounds
    int cnt = 0; float h = 0.f;
    if (lane <= 32) { cnt = ecnt[eb]; h = hepe[eb]; }
    if (lane >= cn) { cnt = 0; h = 0.f; }
    if (cnt > CAPE) cnt = CAPE;

    float sd = h;                                // sum of h over edges of n
#pragma unroll
    for (int d = 32; d >= 1; d >>= 1) sd += __shfl_xor(sd, d, 64);

    int x = cnt;                                 // inclusive scan of cnt
#pragma unroll
    for (int d = 1; d < 64; d <<= 1) {
        int o = __shfl_up(x, d, 64);
        if (lane >= d) x += o;
    }
    int P = __shfl(x, 63, 64);
    if (lane < cn) {
        sOFF[wid][lane] = (u16)(x - cnt);
        sH[wid][lane]   = h;
        sEB[wid][lane]  = (u32)eb * CAPE;
    }

    // --- diagonal term, merged once ---
    float dn    = dinv[row];
    float adiag = A[((size_t)b << 24) + ((size_t)n << 12) + n];
    float cdiag = sd * (adiag + 1.f) * dn;

    const float2* rows2 = (const float2*)rows;
    float2 nvd = rows2[(size_t)row * 64 + lane];
    float2 acc = make_float2(cdiag * nvd.x, cdiag * nvd.y);

    // --- flat pass over all (e,m) pairs ---
    for (int base = 0; base < P; base += 64) {
        int p = base + lane;
        float cc = 0.f; int m = 0;
        if (p < P) {
            int jj = 0;
            while (jj + 1 < cn && sOFF[wid][jj + 1] <= p) jj++;
            m = elists[sEB[wid][jj] + (u32)(p - sOFF[wid][jj])];
            if (m != n) {
                float a = A[((size_t)b << 24) + ((size_t)n << 12) + m];
                if (a != 0.f) cc = sH[wid][jj] * a * dinv[(b << 12) + m];
            }
        }
        u64 mask = __ballot(cc != 0.f);
        while (mask) {
            int src = __ffsll(mask) - 1;
            mask &= mask - 1;
            float cb = __shfl(cc, src, 64);
            int   mb = __shfl(m, src, 64);
            float2 nv = rows2[((size_t)((b << 12) + mb)) * 64 + lane];
            acc.x += cb * nv.x;
            acc.y += cb * nv.y;
        }
    }
    float2* out2 = (float2*)out;
    out2[(size_t)row * 64 + lane] = acc;
}

extern "C" void kernel_launch(void* const* d_in, const int* in_sizes, int n_in,
                              void* d_out, int out_size, void* d_ws, size_t ws_size,
                              hipStream_t stream) {
    const float* node     = (const float*)d_in[0];
    const float* edge     = (const float*)d_in[1];
    const float* node_adj = (const float*)d_in[2];
    const float* D        = (const float*)d_in[3];
    const float* T        = (const float*)d_in[4];
    const float* ew       = (const float*)d_in[5];
    const float* W        = (const float*)d_in[6];
    float* out = (float*)d_out;

    // workspace layout
    char* ws = (char*)d_ws;
    float* hepe  = (float*)ws;                          ws += BB * EE * 4;
    float* dinv  = (float*)ws;                          ws += BB * NN * 4;
    int*   ecnt  = (int*)ws;                            ws += BB * EE * 4;
    u16*   lists = (u16*)ws;                            ws += BB * NN * LSTRIDE * 2;
    u16*   elists= (u16*)ws;                            ws += BB * EE * CAPE * 2;
    size_t small_need = (size_t)(ws - (char*)d_ws);
    float* nodeW = (float*)ws;                          // 8.39 MB (optional)
    bool fuse = ws_size >= small_need + (size_t)BB * NN * FIN * 4;

    k_misc <<<BB * EE / 4 + BB * NN / 256, 256, 0, stream>>>(edge, ew, D, hepe, ecnt, dinv);
    k_lists<<<BB * NN / 4,                 256, 0, stream>>>(T, lists, ecnt, elists);

    if (fuse) {
        k_gemm<<<BB * NN / 32, 256, 0, stream>>>(node, W, nodeW);
        k_main<<<BB * NN / 4,  256, 0, stream>>>(node_adj, nodeW, hepe, dinv,
                                                 lists, ecnt, elists, out);
    } else {
        k_main<<<BB * NN / 4,  256, 0, stream>>>(node_adj, node, hepe, dinv,
                                                 lists, ecnt, elists, out);
        k_gemm<<<BB * NN / 32, 256, 0, stream>>>(out, W, out);
    }
}